// Round 15
// baseline (320.280 us; speedup 1.0000x reference)
//
#include <hip/hip_runtime.h>
#include <hip/hip_fp16.h>

#define DB    768
#define SEQ   2048
#define BATCH 8
#define NTOK  (BATCH*SEQ)      // 16384
#define NFUSE (3*DB)           // 2304 fused QKV output columns
#define NORM_F 0.036084391824351613f
#define ASCALE 512.0f          // attn stored *512 in fp16 to dodge denorm flush
#define INV_ASCALE (1.0f/512.0f)

typedef __attribute__((ext_vector_type(8))) short    short8;
typedef __attribute__((ext_vector_type(8))) _Float16 half8;
typedef __attribute__((ext_vector_type(4))) float    f32x4;
typedef __attribute__((ext_vector_type(4))) float    float4v;

__device__ __forceinline__ float h2f_bits(unsigned short h) {
  __half v; __builtin_memcpy(&v, &h, 2); return __half2float(v);
}
__device__ __forceinline__ unsigned short f2h_bits(float f) {
  __half v = __float2half(f); unsigned short u; __builtin_memcpy(&u, &v, 2); return u;
}

// Async global->LDS, 16B per lane. LDS layout must be LINEAR in lane order.
__device__ __forceinline__ void gl_lds16(const unsigned short* g, unsigned short* l) {
  __builtin_amdgcn_global_load_lds(
      (const __attribute__((address_space(1))) void*)g,
      (__attribute__((address_space(3))) void*)l, 16, 0, 0);
}

// Counted-vmcnt waits (T4): never drain to 0 in the main loop.
#define VMWAIT(N) asm volatile("s_waitcnt vmcnt(" #N ")" ::: "memory")
#define LGKM0()   asm volatile("s_waitcnt lgkmcnt(0)" ::: "memory")
#define SB0()     __builtin_amdgcn_sched_barrier(0)

// =============================================================================
// prep: fused { xhalf (0..6143) | whalf (6144..6575) | compact (6576..6583) }.
// =============================================================================
__global__ __launch_bounds__(256) void prep_kernel(
    const float* __restrict__ X, unsigned short* __restrict__ Xf,
    const float* __restrict__ Wq, const float* __restrict__ Wk,
    const float* __restrict__ Wv, unsigned short* __restrict__ WT,
    const int* __restrict__ mask, int* __restrict__ idx, int* __restrict__ cnt) {
  __shared__ float T[64][68];
  __shared__ int pref[256];
  int bx = blockIdx.x, t = threadIdx.x;

  if (bx < 6144) {
    size_t i8 = ((size_t)bx * 256 + t) * 8;
    float4v v0 = *(const float4v*)(X + i8);
    float4v v1 = *(const float4v*)(X + i8 + 4);
    short8 h;
#pragma unroll
    for (int j = 0; j < 4; j++) h[j] = (short)f2h_bits(v0[j]);
#pragma unroll
    for (int j = 0; j < 4; j++) h[4 + j] = (short)f2h_bits(v1[j]);
    *(short8*)(Xf + i8) = h;
  } else if (bx < 6576) {
    int bw = bx - 6144;
    int w = bw / 144, rem = bw % 144;
    int d0 = (rem / 12) * 64, n0 = (rem % 12) * 64;
    const float* W = (w == 0) ? Wq : ((w == 1) ? Wk : Wv);
    int dl = t >> 4, n4 = (t & 15) * 4;
#pragma unroll
    for (int j = 0; j < 4; j++) {
      float4v v = *(const float4v*)(W + (size_t)(d0 + dl + j * 16) * DB + n0 + n4);
      *(float4v*)&T[dl + j * 16][n4] = v;
    }
    __syncthreads();
    int nl = t >> 2, dc = (t & 3) * 16;
    short8 hb[2];
#pragma unroll
    for (int e = 0; e < 16; e++)
      hb[e >> 3][e & 7] = (short)f2h_bits(T[dc + e][nl]);
    size_t o = ((size_t)w * DB + n0 + nl) * DB + d0 + dc;
    *(short8*)(WT + o) = hb[0]; *(short8*)(WT + o + 8) = hb[1];
  } else {
    int b = bx - 6576;
    const int* m = mask + b * SEQ;
    int mv[8], c = 0, base = t * 8;
#pragma unroll
    for (int j = 0; j < 8; j++) { mv[j] = (m[base + j] != 0); c += mv[j]; }
    pref[t] = c;
    __syncthreads();
    for (int off = 1; off < 256; off <<= 1) {
      int add = (t >= off) ? pref[t - off] : 0;
      __syncthreads();
      pref[t] += add;
      __syncthreads();
    }
    int o = pref[t] - c;
    int* ib = idx + b * SEQ;
#pragma unroll
    for (int j = 0; j < 8; j++) if (mv[j]) ib[o++] = base + j;
    if (t == 255) cnt[b] = pref[255];
  }
}

// =============================================================================
// proj: fused QKV GEMM — BIT-IDENTICAL to R6/R12/R13's 80-82us kernel.
// 256x256, BK=64, 128 KB dbuf LDS, XOR swizzle (slot^=row&7, both-sides),
// 2 bar + VMWAIT(4) per K-tile, setprio, no launch_bounds min-waves.
// =============================================================================
union ProjLDS {
  struct { unsigned short A[2][256 * 64]; unsigned short B[2][256 * 64]; } st; // 128 KB
  unsigned short ep[128][264];         // V-epilogue transpose (66 KB)
};

__global__ __launch_bounds__(512) void proj_kernel(
    const unsigned short* __restrict__ Xf, const unsigned short* __restrict__ WT,
    const float* __restrict__ bq, const float* __restrict__ bk,
    const float* __restrict__ bv,
    const int* __restrict__ idx, const int* __restrict__ cnt,
    unsigned short* __restrict__ Qf, unsigned short* __restrict__ Kf,
    unsigned short* __restrict__ VT) {
  __shared__ ProjLDS u;
  int L = blockIdx.x;
  int g = L & 7, tt = L >> 3;                 // 576 blocks: 72 per xcd (batch g)
  int mt = tt & 7;                            // 256-row m-tile within batch
  int nt = tt >> 3;                           // 0..8
  int z = nt / 3;                             // 0=Q 1=K 2=V
  int nl0 = (nt - z * 3) << 8;                // 0/256/512
  int m0 = g * SEQ + (mt << 8);
  int cb = cnt[g];
  int q0 = mt << 8;
  if (z == 0 && q0 >= cb) return;             // compacted-Q: skip masked tiles
  int tid = threadIdx.x;
  int wave = tid >> 6, lane = tid & 63;
  int wm = wave & 1, wn = wave >> 1;          // 2m x 4n waves, 128x64 each
  int quad = lane >> 4, l16 = lane & 15;

  int srow = tid >> 3;                               // 0..63 within instr
  int sslot8 = (((tid & 7) ^ (srow & 7)) << 3);      // f16 col within K-tile
  size_t gaI[4], gbI[4];
#pragma unroll
  for (int s = 0; s < 4; s++) {
    int rA = s * 64 + srow;
    if (z == 0) {
      int qr = q0 + rA; if (qr >= cb) qr = cb - 1;   // clamp tail (stores guarded)
      gaI[s] = ((size_t)g * SEQ + idx[g * SEQ + qr]) * DB + sslot8;
    } else {
      gaI[s] = (size_t)(m0 + rA) * DB + sslot8;
    }
    gbI[s] = (size_t)((nt << 8) + s * 64 + srow) * DB + sslot8;
  }
  int lofs = tid << 3;                               // shorts within instr block

  auto stageA = [&](int buf, int kt) {
#pragma unroll
    for (int s = 0; s < 4; s++)
      gl_lds16(Xf + gaI[s] + kt * 64, &u.st.A[buf][s * 4096 + lofs]);
  };
  auto stageB = [&](int buf, int kt) {
#pragma unroll
    for (int s = 0; s < 4; s++)
      gl_lds16(WT + gbI[s] + kt * 64, &u.st.B[buf][s * 4096 + lofs]);
  };

  int xorq = l16 & 7;
  auto rdA4 = [&](int mih, int kk, int buf, half8* f) {
    int rb = wm * 128 + mih * 64 + l16;
#pragma unroll
    for (int j = 0; j < 4; j++) {
      int row = rb + j * 16;
      f[j] = *(const half8*)&u.st.A[buf][row * 64 + ((((kk << 2) | quad) ^ xorq) << 3)];
    }
  };
  auto rdB4 = [&](int kk, int buf, half8* f) {
    int rb = wn * 64 + l16;
#pragma unroll
    for (int j = 0; j < 4; j++) {
      int row = rb + j * 16;
      f[j] = *(const half8*)&u.st.B[buf][row * 64 + ((((kk << 2) | quad) ^ xorq) << 3)];
    }
  };

  f32x4 acc[8][4];
#pragma unroll
  for (int mi = 0; mi < 8; mi++)
#pragma unroll
    for (int ni = 0; ni < 4; ni++) acc[mi][ni] = (f32x4){0.f, 0.f, 0.f, 0.f};

  auto mm16 = [&](int mih, const half8* af, const half8* bf) {
    __builtin_amdgcn_s_setprio(1);
#pragma unroll
    for (int j = 0; j < 4; j++)
#pragma unroll
      for (int ni = 0; ni < 4; ni++)
        acc[mih * 4 + j][ni] =
            __builtin_amdgcn_mfma_f32_16x16x32_f16(af[j], bf[ni], acc[mih * 4 + j][ni], 0, 0, 0);
    __builtin_amdgcn_s_setprio(0);
  };

  stageA(0, 0); stageB(0, 0);
  int cur = 0;

  for (int kt = 0; kt < 12; kt++) {           // K = 768 = 12 x 64
    int nxt = cur ^ 1;
    bool pf = kt < 11;
    half8 af[4], bf[4];

    __builtin_amdgcn_s_barrier();             // BAR1: reads of nxt retired
    SB0();
    if (pf) { stageB(nxt, kt + 1); VMWAIT(4); }
    else    { VMWAIT(0); }
    __builtin_amdgcn_s_barrier();             // BAR2: buf[cur] published
    SB0();
    rdA4(0, 0, cur, af); rdB4(0, cur, bf);
    LGKM0(); SB0();
    mm16(0, af, bf);
    SB0();

    rdA4(1, 0, cur, af);
    if (pf) stageA(nxt, kt + 1);
    LGKM0(); SB0();
    mm16(1, af, bf);
    SB0();

    rdA4(0, 1, cur, af); rdB4(1, cur, bf);
    LGKM0(); SB0();
    mm16(0, af, bf);
    SB0();

    rdA4(1, 1, cur, af);
    LGKM0(); SB0();
    mm16(1, af, bf);
    SB0();

    cur = nxt;
  }

  const float* bias = (z == 0) ? bq : ((z == 1) ? bk : bv);
  if (z == 2) {
    // ---- V: transpose 256x256 tile through LDS in two 128-col passes ----
    __syncthreads();                          // all frag reads of u.st done
#pragma unroll
    for (int hh = 0; hh < 2; hh++) {
      if ((wn >> 1) == hh) {                  // waves holding cols [hh*128,..)
#pragma unroll
        for (int mi = 0; mi < 8; mi++)
#pragma unroll
          for (int ni = 0; ni < 4; ni++)
#pragma unroll
            for (int r = 0; r < 4; r++) {
              int ml = wm * 128 + mi * 16 + quad * 4 + r;   // 0..255 (s-local)
              int nl = (wn & 1) * 64 + ni * 16 + l16;       // 0..127 within half
              u.ep[nl][ml] = f2h_bits(acc[mi][ni][r] + bias[nl0 + hh * 128 + nl]);
            }
      }
      __syncthreads();
      int vl = tid >> 2, s0 = (tid & 3) << 6;   // 64 shorts per thread
      size_t vbase = ((size_t)g * DB + nl0 + hh * 128 + vl) * SEQ + (mt << 8) + s0;
#pragma unroll
      for (int j = 0; j < 8; j++) {
        short8 v = *(const short8*)&u.ep[vl][s0 + j * 8];
        *(short8*)(VT + vbase + j * 8) = v;
      }
      __syncthreads();                         // ep reused next pass
    }
  } else {
#pragma unroll
    for (int mi = 0; mi < 8; mi++)
#pragma unroll
      for (int r = 0; r < 4; r++) {
        int ml = wm * 128 + mi * 16 + quad * 4 + r;
        if (z == 0 && q0 + ml >= cb) continue;          // guarded compacted tail
        size_t rowbase = (size_t)(m0 + ml) * DB;        // compacted row for Q
#pragma unroll
        for (int ni = 0; ni < 4; ni++) {
          int nl = nl0 + wn * 64 + ni * 16 + l16;
          unsigned short h = f2h_bits(acc[mi][ni][r] + bias[nl]);
          if (z == 0) Qf[rowbase + nl] = h;
          else        Kf[rowbase + nl] = h;
        }
      }
  }
}

// =============================================================================
// vmean (R12-proven standalone): Vmean[b][n] = mean_s VT[b][n][s].
// =============================================================================
__global__ __launch_bounds__(256) void vmean_kernel(
    const unsigned short* __restrict__ VT, float* __restrict__ Vmean) {
  int bn = blockIdx.x;
  const unsigned short* p = VT + (size_t)bn * SEQ;
  int t = threadIdx.x, wave = t >> 6, lane = t & 63;
  short8 hv = *(const short8*)(p + t * 8);
  float s = 0.f;
#pragma unroll
  for (int j = 0; j < 8; j++) s += h2f_bits((unsigned short)hv[j]);
#pragma unroll
  for (int off = 32; off >= 1; off >>= 1) s += __shfl_down(s, off);
  __shared__ float red[4];
  if (lane == 0) red[wave] = s;
  __syncthreads();
  if (t == 0) Vmean[bn] = (red[0] + red[1] + red[2] + red[3]) * (1.0f / SEQ);
}

// =============================================================================
// scores256: SC[b][qc][t] = Qf[qc].Kf[t] — proj's proven 256^2 K-loop.
// FIX vs R14: correct tile decomposition.  512 blocks = 8 batches x 64 tiles;
// tt in [0,64): mt = tt&7 (8 q-tiles of 256, INNER), nt = tt>>3 (8 t-tiles).
// R14's mt=tt&3/nt=tt>>2 read Kf rows up to 3840 (past batch) and stored
// gt up to 3840 (row overflow) -> absmax 0.133.  Blocks with q0>=cb skip.
// =============================================================================
struct ScoresLDS {
  unsigned short A[2][256 * 64];
  unsigned short B[2][256 * 64];               // 128 KB
};

__global__ __launch_bounds__(512) void scores256_kernel(
    const unsigned short* __restrict__ Qf, const unsigned short* __restrict__ Kf,
    const int* __restrict__ cnt, unsigned short* __restrict__ SC) {
  __shared__ ScoresLDS u;
  int L = blockIdx.x;
  int g = L & 7, tt = L >> 3;                 // 512 blocks: 64 per xcd (batch g)
  int mt = tt & 7;                            // 8 q-tiles of 256 (inner)
  int nt = tt >> 3;                           // 8 t-tiles of 256 (outer)
  int cb = cnt[g];
  int q0 = mt << 8;
  if (q0 >= cb) return;                       // compacted: skip masked q-tiles
  int tid = threadIdx.x;
  int wave = tid >> 6, lane = tid & 63;
  int wm = wave & 1, wn = wave >> 1;          // 2m x 4n waves, 128x64 each
  int quad = lane >> 4, l16 = lane & 15;

  int srow = tid >> 3;                               // 0..63 within instr
  int sslot8 = (((tid & 7) ^ (srow & 7)) << 3);      // f16 col within K-tile
  size_t gaI[4], gbI[4];
#pragma unroll
  for (int s = 0; s < 4; s++) {
    int qr = q0 + s * 64 + srow; if (qr >= cb) qr = cb - 1;  // clamp (stores guarded)
    gaI[s] = ((size_t)g * SEQ + qr) * DB + sslot8;           // Qf compacted rows
    gbI[s] = ((size_t)g * SEQ + (nt << 8) + s * 64 + srow) * DB + sslot8;
  }
  int lofs = tid << 3;

  auto stageA = [&](int buf, int kt) {
#pragma unroll
    for (int s = 0; s < 4; s++)
      gl_lds16(Qf + gaI[s] + kt * 64, &u.A[buf][s * 4096 + lofs]);
  };
  auto stageB = [&](int buf, int kt) {
#pragma unroll
    for (int s = 0; s < 4; s++)
      gl_lds16(Kf + gbI[s] + kt * 64, &u.B[buf][s * 4096 + lofs]);
  };

  int xorq = l16 & 7;
  auto rdA4 = [&](int mih, int kk, int buf, half8* f) {
    int rb = wm * 128 + mih * 64 + l16;
#pragma unroll
    for (int j = 0; j < 4; j++) {
      int row = rb + j * 16;
      f[j] = *(const half8*)&u.A[buf][row * 64 + ((((kk << 2) | quad) ^ xorq) << 3)];
    }
  };
  auto rdB4 = [&](int kk, int buf, half8* f) {
    int rb = wn * 64 + l16;
#pragma unroll
    for (int j = 0; j < 4; j++) {
      int row = rb + j * 16;
      f[j] = *(const half8*)&u.B[buf][row * 64 + ((((kk << 2) | quad) ^ xorq) << 3)];
    }
  };

  f32x4 acc[8][4];
#pragma unroll
  for (int mi = 0; mi < 8; mi++)
#pragma unroll
    for (int ni = 0; ni < 4; ni++) acc[mi][ni] = (f32x4){0.f, 0.f, 0.f, 0.f};

  auto mm16 = [&](int mih, const half8* af, const half8* bf) {
    __builtin_amdgcn_s_setprio(1);
#pragma unroll
    for (int j = 0; j < 4; j++)
#pragma unroll
      for (int ni = 0; ni < 4; ni++)
        acc[mih * 4 + j][ni] =
            __builtin_amdgcn_mfma_f32_16x16x32_f16(af[j], bf[ni], acc[mih * 4 + j][ni], 0, 0, 0);
    __builtin_amdgcn_s_setprio(0);
  };

  stageA(0, 0); stageB(0, 0);
  int cur = 0;

  for (int kt = 0; kt < 12; kt++) {           // K = 768 = 12 x 64
    int nxt = cur ^ 1;
    bool pf = kt < 11;
    half8 af[4], bf[4];

    __builtin_amdgcn_s_barrier();             // BAR1
    SB0();
    if (pf) { stageB(nxt, kt + 1); VMWAIT(4); }
    else    { VMWAIT(0); }
    __builtin_amdgcn_s_barrier();             // BAR2
    SB0();
    rdA4(0, 0, cur, af); rdB4(0, cur, bf);
    LGKM0(); SB0();
    mm16(0, af, bf);
    SB0();

    rdA4(1, 0, cur, af);
    if (pf) stageA(nxt, kt + 1);
    LGKM0(); SB0();
    mm16(1, af, bf);
    SB0();

    rdA4(0, 1, cur, af); rdB4(1, cur, bf);
    LGKM0(); SB0();
    mm16(0, af, bf);
    SB0();

    rdA4(1, 1, cur, af);
    LGKM0(); SB0();
    mm16(1, af, bf);
    SB0();

    cur = nxt;
  }

#pragma unroll
  for (int mi = 0; mi < 8; mi++)
#pragma unroll
    for (int r = 0; r < 4; r++) {
      int qc = q0 + wm * 128 + mi * 16 + quad * 4 + r;
      if (qc < cb) {
#pragma unroll
        for (int ni = 0; ni < 4; ni++) {
          int gt = (nt << 8) + wn * 64 + ni * 16 + l16;
          SC[((size_t)g * SEQ + qc) * SEQ + gt] = f2h_bits(acc[mi][ni][r]);
        }
      }
    }
}

// =============================================================================
// sf: fused launch { stats (0..16383) | fill (16384..32767) }.  R13-proven.
// =============================================================================
__global__ __launch_bounds__(256) void sf_kernel(
    const unsigned short* __restrict__ SC, const int* __restrict__ cnt,
    float* __restrict__ Mq, float* __restrict__ Sq,
    const int* __restrict__ mask, const float* __restrict__ Vmean,
    float* __restrict__ out) {
  __shared__ float red[8];
  int bx = blockIdx.x;

  if (bx >= NTOK) {
    int row = bx - NTOK;
    if (mask[row] != 0) return;
    const float* vm = Vmean + (row >> 11) * DB;
    float* o = out + (size_t)row * DB;
    for (int n = threadIdx.x; n < DB; n += 256) o[n] = vm[n] * NORM_F;
    return;
  }

  int b = bx >> 11, qc = bx & 2047;
  if (qc >= cnt[b]) return;
  const unsigned short* p = SC + ((size_t)b * SEQ + qc) * SEQ;
  int tid = threadIdx.x;

  short8 hv = *(const short8*)(p + (tid << 3));
  float v[8];
#pragma unroll
  for (int j = 0; j < 8; j++) v[j] = h2f_bits((unsigned short)hv[j]);

  float m = v[0];
#pragma unroll
  for (int j = 1; j < 8; j++) m = fmaxf(m, v[j]);
#pragma unroll
  for (int off = 32; off >= 1; off >>= 1) m = fmaxf(m, __shfl_down(m, off));

  int w = tid >> 6;
  if ((tid & 63) == 0) red[w] = m;
  __syncthreads();
  m = fmaxf(fmaxf(red[0], red[1]), fmaxf(red[2], red[3]));

  float s = 0.f;
#pragma unroll
  for (int j = 0; j < 8; j++) s += __expf(v[j] - m);
#pragma unroll
  for (int off = 32; off >= 1; off >>= 1) s += __shfl_down(s, off);
  if ((tid & 63) == 0) red[4 + w] = s;
  __syncthreads();
  if (tid == 0) {
    float L = red[4] + red[5] + red[6] + red[7];
    Mq[(size_t)b * SEQ + qc] = m;
    Sq[(size_t)b * SEQ + qc] = NORM_F * ASCALE / L;
  }
}

// =============================================================================
// pv: out[idx[qc]][v] = (1/ASCALE) * sum_t exp(s-m)*scale * V[t][v].
// A-path reg-staged (exp fused); B via gl_lds; 3-buf ring, VMWAIT(3).
// R12/R13-proven, unchanged.
// =============================================================================
__global__ __launch_bounds__(256) void pv_kernel(
    const unsigned short* __restrict__ SC, const unsigned short* __restrict__ VT,
    const int* __restrict__ idx, const int* __restrict__ cnt,
    const float* __restrict__ Mq, const float* __restrict__ Sq,
    float* __restrict__ out) {
  __shared__ unsigned short As[3][64 * 32], Bs[3][128 * 32];   // 36 KB
  int L = blockIdx.x;
  int b = L & 7, tt = L >> 3;                 // 192 per batch
  int q0 = (tt / 6) << 6;                     // 64-row q tiles, q outer
  int v0 = (tt % 6) << 7;                     // v inner (SC stripe L2-reused 6x)
  int cb = cnt[b];
  if (q0 >= cb) return;
  int tid = threadIdx.x;
  int wave = tid >> 6, lane = tid & 63;
  int wm = wave & 1, wn = wave >> 1;          // 2m x 2n waves, each 32x64
  int quad = lane >> 4, l16 = lane & 15;

  int rowA = tid >> 2, colA = (tid & 3) << 3;
  size_t gaA = ((size_t)b * SEQ + q0 + rowA) * SEQ + colA;  // rows>=cb garbage, guarded
  int lofsA = tid << 3;
  float mrow = Mq[(size_t)b * SEQ + q0 + rowA];   // rows>=cb: garbage, dead rows
  float srow = Sq[(size_t)b * SEQ + q0 + rowA];
  size_t gb[2]; int lofsB[2];
#pragma unroll
  for (int r = 0; r < 2; r++) {
    int li = r * 256 + tid;
    int row = li >> 2, col = (li & 3) << 3;
    gb[r] = ((size_t)b * DB + v0 + row) * SEQ + col;
    lofsB[r] = li << 3;
  }

  f32x4 acc[2][4];
#pragma unroll
  for (int mi = 0; mi < 2; mi++)
#pragma unroll
    for (int ni = 0; ni < 4; ni++) acc[mi][ni] = (f32x4){0.f, 0.f, 0.f, 0.f};

  short8 va[3];   // A reg-stage ring; statically indexed only

  auto ldA = [&](int buf, int kt) {
    if (buf == 0) va[0] = *(const short8*)(SC + gaA + kt);
    else if (buf == 1) va[1] = *(const short8*)(SC + gaA + kt);
    else va[2] = *(const short8*)(SC + gaA + kt);
  };
  auto stageB2 = [&](int buf, int kt) {
#pragma unroll
    for (int r = 0; r < 2; r++)
      gl_lds16(VT + gb[r] + kt, &Bs[buf][lofsB[r]]);
  };
  auto procA = [&](int buf) {
    short8 src = (buf == 0) ? va[0] : ((buf == 1) ? va[1] : va[2]);
    short8 w;
#pragma unroll
    for (int j = 0; j < 8; j++) {
      float x = h2f_bits((unsigned short)src[j]);
      w[j] = (short)f2h_bits(__expf(x - mrow) * srow);
    }
    *(short8*)&As[buf][lofsA] = w;
  };
  auto compute = [&](int buf) {
    half8 af[2], bfr[4];
#pragma unroll
    for (int mi = 0; mi < 2; mi++)
      af[mi] = *(const half8*)&As[buf][(wm * 32 + mi * 16 + l16) * 32 + quad * 8];
#pragma unroll
    for (int ni = 0; ni < 4; ni++)
      bfr[ni] = *(const half8*)&Bs[buf][(wn * 64 + ni * 16 + l16) * 32 + quad * 8];
    __builtin_amdgcn_s_setprio(1);
#pragma unroll
    for (int mi = 0; mi < 2; mi++)
#pragma unroll
      for (int ni = 0; ni < 4; ni++)
        acc[mi][ni] = __builtin_amdgcn_mfma_f32_16x16x32_f16(af[mi], bfr[ni], acc[mi][ni], 0, 0, 0);
    __builtin_amdgcn_s_setprio(0);
  };

  auto body = [&](int it, int C, int S) {
    VMWAIT(3);                 // stage(it) landed: va[C] + all waves' Bs[C]
    procA(C);                  // exp + ds_write A
    LGKM0();                   // retire ds_write (and prior frag reads: WAR)
    __builtin_amdgcn_s_barrier();
    SB0();
    if (it < 62) { ldA(S, (it + 2) * 32); stageB2(S, (it + 2) * 32); }
    compute(C);
    SB0();
  };

  ldA(0, 0);  stageB2(0, 0);
  ldA(1, 32); stageB2(1, 32);
  for (int i3 = 0; i3 < 63; i3 += 3) {
    body(i3, 0, 2);
    body(i3 + 1, 1, 0);
    body(i3 + 2, 2, 1);
  }
  // it = 63 (final tile, buf 0)
  VMWAIT(0);
  procA(0);
  LGKM0();
  __builtin_amdgcn_s_barrier();
  SB0();
  compute(0);

#pragma unroll
  for (int mi = 0; mi < 2; mi++)
#pragma unroll
    for (int r = 0; r < 4; r++) {
      int qc = q0 + wm * 32 + mi * 16 + quad * 4 + r;
      if (qc < cb) {
        int q = idx[b * SEQ + qc];
#pragma unroll
        for (int ni = 0; ni < 4; ni++) {
          int gv = v0 + wn * 64 + ni * 16 + l16;
          out[((size_t)b * SEQ + q) * DB + gv] = acc[mi][ni][r] * INV_ASCALE;
        }
      }
    }
}

// =============================================================================
extern "C" void kernel_launch(void* const* d_in, const int* in_sizes, int n_in,
                              void* d_out, int out_size, void* d_ws, size_t ws_size,
                              hipStream_t stream) {
  const float* x    = (const float*)d_in[0];
  const int*   mask = (const int*)d_in[1];
  const float* Wq   = (const float*)d_in[2];
  const float* bq   = (const float*)d_in[3];
  const float* Wk   = (const float*)d_in[4];
  const float* bk   = (const float*)d_in[5];
  const float* Wv   = (const float*)d_in[6];
  const float* bv   = (const float*)d_in[7];
  float* out = (float*)d_out;
  char* ws = (char*)d_ws;

  const size_t TOKH = (size_t)NTOK * DB * 2;                 // 25,165,824 B
  unsigned short* SC = (unsigned short*)ws;
  unsigned short* Xf = (unsigned short*)ws;
  unsigned short* WT = (unsigned short*)(ws + TOKH);
  const size_t SCSZ = (size_t)BATCH * SEQ * SEQ * 2;         // 67,108,864 B
  unsigned short* Qf = (unsigned short*)(ws + SCSZ);
  unsigned short* Kf = Qf + (size_t)NTOK * DB;
  unsigned short* VT = Kf + (size_t)NTOK * DB;
  int*   idx   = (int*)(ws + SCSZ + 3 * TOKH);
  int*   cnt   = idx + NTOK;
  float* Vmean = (float*)(cnt + 16);
  float* Mq    = Vmean + BATCH * DB;
  float* Sq    = Mq + NTOK;

  prep_kernel<<<6584, 256, 0, stream>>>(x, Xf, Wq, Wk, Wv, WT, mask, idx, cnt);
  proj_kernel<<<(NFUSE / 256) * (NTOK / 256), 512, 0, stream>>>(
      Xf, WT, bq, bk, bv, idx, cnt, Qf, Kf, VT);
  vmean_kernel<<<BATCH * DB, 256, 0, stream>>>(VT, Vmean);
  scores256_kernel<<<(SEQ / 256) * (SEQ / 256) * BATCH, 512, 0, stream>>>(
      Qf, Kf, cnt, SC);
  sf_kernel<<<2 * NTOK, 256, 0, stream>>>(
      SC, cnt, Mq, Sq, mask, Vmean, out);
  pv_kernel<<<(SEQ / 64) * (DB / 128) * BATCH, 256, 0, stream>>>(
      SC, VT, idx, cnt, Mq, Sq, out);
}

// Round 16
// 311.804 us; speedup vs baseline: 1.0272x; 1.0272x over previous
//
#include <hip/hip_runtime.h>
#include <hip/hip_fp16.h>

#define DB    768
#define SEQ   2048
#define BATCH 8
#define NTOK  (BATCH*SEQ)      // 16384
#define NFUSE (3*DB)           // 2304 fused QKV output columns
#define NORM_F 0.036084391824351613f
#define ASCALE 512.0f          // attn stored *512 in fp16 to dodge denorm flush
#define INV_ASCALE (1.0f/512.0f)

typedef __attribute__((ext_vector_type(8))) short    short8;
typedef __attribute__((ext_vector_type(8))) _Float16 half8;
typedef __attribute__((ext_vector_type(4))) float    f32x4;
typedef __attribute__((ext_vector_type(4))) float    float4v;

__device__ __forceinline__ float h2f_bits(unsigned short h) {
  __half v; __builtin_memcpy(&v, &h, 2); return __half2float(v);
}
__device__ __forceinline__ unsigned short f2h_bits(float f) {
  __half v = __float2half(f); unsigned short u; __builtin_memcpy(&u, &v, 2); return u;
}

// Async global->LDS, 16B per lane. LDS layout must be LINEAR in lane order.
__device__ __forceinline__ void gl_lds16(const unsigned short* g, unsigned short* l) {
  __builtin_amdgcn_global_load_lds(
      (const __attribute__((address_space(1))) void*)g,
      (__attribute__((address_space(3))) void*)l, 16, 0, 0);
}

// Counted-vmcnt waits (T4): never drain to 0 in the main loop.
#define VMWAIT(N) asm volatile("s_waitcnt vmcnt(" #N ")" ::: "memory")
#define LGKM0()   asm volatile("s_waitcnt lgkmcnt(0)" ::: "memory")
#define SB0()     __builtin_amdgcn_sched_barrier(0)

// =============================================================================
// prep: fused { xhalf (0..6143) | whalf (6144..6575) | compact (6576..6583) }.
// =============================================================================
__global__ __launch_bounds__(256) void prep_kernel(
    const float* __restrict__ X, unsigned short* __restrict__ Xf,
    const float* __restrict__ Wq, const float* __restrict__ Wk,
    const float* __restrict__ Wv, unsigned short* __restrict__ WT,
    const int* __restrict__ mask, int* __restrict__ idx, int* __restrict__ cnt) {
  __shared__ float T[64][68];
  __shared__ int pref[256];
  int bx = blockIdx.x, t = threadIdx.x;

  if (bx < 6144) {
    size_t i8 = ((size_t)bx * 256 + t) * 8;
    float4v v0 = *(const float4v*)(X + i8);
    float4v v1 = *(const float4v*)(X + i8 + 4);
    short8 h;
#pragma unroll
    for (int j = 0; j < 4; j++) h[j] = (short)f2h_bits(v0[j]);
#pragma unroll
    for (int j = 0; j < 4; j++) h[4 + j] = (short)f2h_bits(v1[j]);
    *(short8*)(Xf + i8) = h;
  } else if (bx < 6576) {
    int bw = bx - 6144;
    int w = bw / 144, rem = bw % 144;
    int d0 = (rem / 12) * 64, n0 = (rem % 12) * 64;
    const float* W = (w == 0) ? Wq : ((w == 1) ? Wk : Wv);
    int dl = t >> 4, n4 = (t & 15) * 4;
#pragma unroll
    for (int j = 0; j < 4; j++) {
      float4v v = *(const float4v*)(W + (size_t)(d0 + dl + j * 16) * DB + n0 + n4);
      *(float4v*)&T[dl + j * 16][n4] = v;
    }
    __syncthreads();
    int nl = t >> 2, dc = (t & 3) * 16;
    short8 hb[2];
#pragma unroll
    for (int e = 0; e < 16; e++)
      hb[e >> 3][e & 7] = (short)f2h_bits(T[dc + e][nl]);
    size_t o = ((size_t)w * DB + n0 + nl) * DB + d0 + dc;
    *(short8*)(WT + o) = hb[0]; *(short8*)(WT + o + 8) = hb[1];
  } else {
    int b = bx - 6576;
    const int* m = mask + b * SEQ;
    int mv[8], c = 0, base = t * 8;
#pragma unroll
    for (int j = 0; j < 8; j++) { mv[j] = (m[base + j] != 0); c += mv[j]; }
    pref[t] = c;
    __syncthreads();
    for (int off = 1; off < 256; off <<= 1) {
      int add = (t >= off) ? pref[t - off] : 0;
      __syncthreads();
      pref[t] += add;
      __syncthreads();
    }
    int o = pref[t] - c;
    int* ib = idx + b * SEQ;
#pragma unroll
    for (int j = 0; j < 8; j++) if (mv[j]) ib[o++] = base + j;
    if (t == 255) cnt[b] = pref[255];
  }
}

// =============================================================================
// proj: fused QKV GEMM — BIT-IDENTICAL to R6/R12/R13's 80-82us kernel.
// 256x256, BK=64, 128 KB dbuf LDS, XOR swizzle (slot^=row&7, both-sides),
// 2 bar + VMWAIT(4) per K-tile, setprio, no launch_bounds min-waves.
// =============================================================================
union ProjLDS {
  struct { unsigned short A[2][256 * 64]; unsigned short B[2][256 * 64]; } st; // 128 KB
  unsigned short ep[128][264];         // V-epilogue transpose (66 KB)
};

__global__ __launch_bounds__(512) void proj_kernel(
    const unsigned short* __restrict__ Xf, const unsigned short* __restrict__ WT,
    const float* __restrict__ bq, const float* __restrict__ bk,
    const float* __restrict__ bv,
    const int* __restrict__ idx, const int* __restrict__ cnt,
    unsigned short* __restrict__ Qf, unsigned short* __restrict__ Kf,
    unsigned short* __restrict__ VT) {
  __shared__ ProjLDS u;
  int L = blockIdx.x;
  int g = L & 7, tt = L >> 3;                 // 576 blocks: 72 per xcd (batch g)
  int mt = tt & 7;                            // 256-row m-tile within batch
  int nt = tt >> 3;                           // 0..8
  int z = nt / 3;                             // 0=Q 1=K 2=V
  int nl0 = (nt - z * 3) << 8;                // 0/256/512
  int m0 = g * SEQ + (mt << 8);
  int cb = cnt[g];
  int q0 = mt << 8;
  if (z == 0 && q0 >= cb) return;             // compacted-Q: skip masked tiles
  int tid = threadIdx.x;
  int wave = tid >> 6, lane = tid & 63;
  int wm = wave & 1, wn = wave >> 1;          // 2m x 4n waves, 128x64 each
  int quad = lane >> 4, l16 = lane & 15;

  int srow = tid >> 3;                               // 0..63 within instr
  int sslot8 = (((tid & 7) ^ (srow & 7)) << 3);      // f16 col within K-tile
  size_t gaI[4], gbI[4];
#pragma unroll
  for (int s = 0; s < 4; s++) {
    int rA = s * 64 + srow;
    if (z == 0) {
      int qr = q0 + rA; if (qr >= cb) qr = cb - 1;   // clamp tail (stores guarded)
      gaI[s] = ((size_t)g * SEQ + idx[g * SEQ + qr]) * DB + sslot8;
    } else {
      gaI[s] = (size_t)(m0 + rA) * DB + sslot8;
    }
    gbI[s] = (size_t)((nt << 8) + s * 64 + srow) * DB + sslot8;
  }
  int lofs = tid << 3;                               // shorts within instr block

  auto stageA = [&](int buf, int kt) {
#pragma unroll
    for (int s = 0; s < 4; s++)
      gl_lds16(Xf + gaI[s] + kt * 64, &u.st.A[buf][s * 4096 + lofs]);
  };
  auto stageB = [&](int buf, int kt) {
#pragma unroll
    for (int s = 0; s < 4; s++)
      gl_lds16(WT + gbI[s] + kt * 64, &u.st.B[buf][s * 4096 + lofs]);
  };

  int xorq = l16 & 7;
  auto rdA4 = [&](int mih, int kk, int buf, half8* f) {
    int rb = wm * 128 + mih * 64 + l16;
#pragma unroll
    for (int j = 0; j < 4; j++) {
      int row = rb + j * 16;
      f[j] = *(const half8*)&u.st.A[buf][row * 64 + ((((kk << 2) | quad) ^ xorq) << 3)];
    }
  };
  auto rdB4 = [&](int kk, int buf, half8* f) {
    int rb = wn * 64 + l16;
#pragma unroll
    for (int j = 0; j < 4; j++) {
      int row = rb + j * 16;
      f[j] = *(const half8*)&u.st.B[buf][row * 64 + ((((kk << 2) | quad) ^ xorq) << 3)];
    }
  };

  f32x4 acc[8][4];
#pragma unroll
  for (int mi = 0; mi < 8; mi++)
#pragma unroll
    for (int ni = 0; ni < 4; ni++) acc[mi][ni] = (f32x4){0.f, 0.f, 0.f, 0.f};

  auto mm16 = [&](int mih, const half8* af, const half8* bf) {
    __builtin_amdgcn_s_setprio(1);
#pragma unroll
    for (int j = 0; j < 4; j++)
#pragma unroll
      for (int ni = 0; ni < 4; ni++)
        acc[mih * 4 + j][ni] =
            __builtin_amdgcn_mfma_f32_16x16x32_f16(af[j], bf[ni], acc[mih * 4 + j][ni], 0, 0, 0);
    __builtin_amdgcn_s_setprio(0);
  };

  stageA(0, 0); stageB(0, 0);
  int cur = 0;

  for (int kt = 0; kt < 12; kt++) {           // K = 768 = 12 x 64
    int nxt = cur ^ 1;
    bool pf = kt < 11;
    half8 af[4], bf[4];

    __builtin_amdgcn_s_barrier();             // BAR1: reads of nxt retired
    SB0();
    if (pf) { stageB(nxt, kt + 1); VMWAIT(4); }
    else    { VMWAIT(0); }
    __builtin_amdgcn_s_barrier();             // BAR2: buf[cur] published
    SB0();
    rdA4(0, 0, cur, af); rdB4(0, cur, bf);
    LGKM0(); SB0();
    mm16(0, af, bf);
    SB0();

    rdA4(1, 0, cur, af);
    if (pf) stageA(nxt, kt + 1);
    LGKM0(); SB0();
    mm16(1, af, bf);
    SB0();

    rdA4(0, 1, cur, af); rdB4(1, cur, bf);
    LGKM0(); SB0();
    mm16(0, af, bf);
    SB0();

    rdA4(1, 1, cur, af);
    LGKM0(); SB0();
    mm16(1, af, bf);
    SB0();

    cur = nxt;
  }

  const float* bias = (z == 0) ? bq : ((z == 1) ? bk : bv);
  if (z == 2) {
    // ---- V: transpose 256x256 tile through LDS in two 128-col passes ----
    __syncthreads();                          // all frag reads of u.st done
#pragma unroll
    for (int hh = 0; hh < 2; hh++) {
      if ((wn >> 1) == hh) {                  // waves holding cols [hh*128,..)
#pragma unroll
        for (int mi = 0; mi < 8; mi++)
#pragma unroll
          for (int ni = 0; ni < 4; ni++)
#pragma unroll
            for (int r = 0; r < 4; r++) {
              int ml = wm * 128 + mi * 16 + quad * 4 + r;   // 0..255 (s-local)
              int nl = (wn & 1) * 64 + ni * 16 + l16;       // 0..127 within half
              u.ep[nl][ml] = f2h_bits(acc[mi][ni][r] + bias[nl0 + hh * 128 + nl]);
            }
      }
      __syncthreads();
      int vl = tid >> 2, s0 = (tid & 3) << 6;   // 64 shorts per thread
      size_t vbase = ((size_t)g * DB + nl0 + hh * 128 + vl) * SEQ + (mt << 8) + s0;
#pragma unroll
      for (int j = 0; j < 8; j++) {
        short8 v = *(const short8*)&u.ep[vl][s0 + j * 8];
        *(short8*)(VT + vbase + j * 8) = v;
      }
      __syncthreads();                         // ep reused next pass
    }
  } else {
#pragma unroll
    for (int mi = 0; mi < 8; mi++)
#pragma unroll
      for (int r = 0; r < 4; r++) {
        int ml = wm * 128 + mi * 16 + quad * 4 + r;
        if (z == 0 && q0 + ml >= cb) continue;          // guarded compacted tail
        size_t rowbase = (size_t)(m0 + ml) * DB;        // compacted row for Q
#pragma unroll
        for (int ni = 0; ni < 4; ni++) {
          int nl = nl0 + wn * 64 + ni * 16 + l16;
          unsigned short h = f2h_bits(acc[mi][ni][r] + bias[nl]);
          if (z == 0) Qf[rowbase + nl] = h;
          else        Kf[rowbase + nl] = h;
        }
      }
  }
}

// =============================================================================
// sv: fused launch { scores (blocks 0..2047) | vmean (2048..8191) }.
// R13-proven arrangement.  NEW: 4-slot XOR swizzle on A/B (slot^=row&3,
// both-sides: pre-swizzled gl_lds SOURCE + swizzled frag reads) — proj's
// verified conflict fix ported to the 32-col tile (was ~8-way on ds_read_b128).
// =============================================================================
__global__ __launch_bounds__(256) void sv_kernel(
    const unsigned short* __restrict__ Qf, const unsigned short* __restrict__ Kf,
    const int* __restrict__ cnt, unsigned short* __restrict__ SC,
    const unsigned short* __restrict__ VT, float* __restrict__ Vmean) {
  __shared__ unsigned short As[3][128 * 32], Bs[3][128 * 32];   // 48 KB
  __shared__ float red[4];
  int bx = blockIdx.x;

  if (bx >= 2048) {
    // ---- vmean: Vmean[b][n] = mean_s VT[b][n][s] ----
    int bn = bx - 2048;
    const unsigned short* p = VT + (size_t)bn * SEQ;
    int t = threadIdx.x, wave = t >> 6, lane = t & 63;
    short8 hv = *(const short8*)(p + t * 8);
    float s = 0.f;
#pragma unroll
    for (int j = 0; j < 8; j++) s += h2f_bits((unsigned short)hv[j]);
#pragma unroll
    for (int off = 32; off >= 1; off >>= 1) s += __shfl_down(s, off);
    if (lane == 0) red[wave] = s;
    __syncthreads();
    if (t == 0) Vmean[bn] = (red[0] + red[1] + red[2] + red[3]) * (1.0f / SEQ);
    return;
  }

  // ---- scores: SC[b][qc][t] = Qf[qc] . Kf[t]  (R3 ring + swizzle) ----
  int L = bx;
  int b = L & 7, tt = L >> 3;                 // 2048 blocks: 256 per xcd
  int q0 = (tt >> 4) << 7;                    // q outer
  int t0 = (tt & 15) << 7;                    // t inner
  int cb = cnt[b];
  if (q0 >= cb) return;
  int tid = threadIdx.x;
  int wave = tid >> 6, lane = tid & 63;
  int wm = wave & 1, wn = wave >> 1;
  int quad = lane >> 4, l16 = lane & 15;

  size_t ga[2], gb[2]; int lofs[2];
#pragma unroll
  for (int r = 0; r < 2; r++) {
    int li = r * 256 + tid;
    int row = li >> 2;
    int col = (((li & 3) ^ (row & 3)) << 3);          // inverse-swizzled source
    ga[r] = ((size_t)b * SEQ + q0 + row) * DB + col;  // rows>=cb: garbage, guarded
    gb[r] = ((size_t)b * SEQ + t0 + row) * DB + col;
    lofs[r] = li << 3;                                // linear LDS dest
  }

  f32x4 acc[4][4];
#pragma unroll
  for (int mi = 0; mi < 4; mi++)
#pragma unroll
    for (int ni = 0; ni < 4; ni++) acc[mi][ni] = (f32x4){0.f, 0.f, 0.f, 0.f};

  auto stage = [&](int buf, int kt) {
#pragma unroll
    for (int r = 0; r < 2; r++) {
      gl_lds16(Qf + ga[r] + kt, &As[buf][lofs[r]]);
      gl_lds16(Kf + gb[r] + kt, &Bs[buf][lofs[r]]);
    }
  };
  int xorq = l16 & 3;                                 // read-side XOR (row&3==l16&3)
  auto compute = [&](int buf) {
    half8 af[4], bfr[4];
#pragma unroll
    for (int mi = 0; mi < 4; mi++)
      af[mi] = *(const half8*)&As[buf][(wm * 64 + mi * 16 + l16) * 32 + ((quad ^ xorq) << 3)];
#pragma unroll
    for (int ni = 0; ni < 4; ni++)
      bfr[ni] = *(const half8*)&Bs[buf][(wn * 64 + ni * 16 + l16) * 32 + ((quad ^ xorq) << 3)];
    __builtin_amdgcn_s_setprio(1);
#pragma unroll
    for (int mi = 0; mi < 4; mi++)
#pragma unroll
      for (int ni = 0; ni < 4; ni++)
        acc[mi][ni] = __builtin_amdgcn_mfma_f32_16x16x32_f16(af[mi], bfr[ni], acc[mi][ni], 0, 0, 0);
    __builtin_amdgcn_s_setprio(0);
  };

  stage(0, 0);
  stage(1, 32);
  int bc = 0, bs = 2;
  for (int it = 0; it < 23; it++) {
    VMWAIT(4);
    __builtin_amdgcn_s_barrier();
    __builtin_amdgcn_sched_barrier(0);
    if (it < 22) stage(bs, (it + 2) * 32);
    compute(bc);
    __builtin_amdgcn_sched_barrier(0);
    bc = (bc == 2) ? 0 : bc + 1;
    bs = (bs == 2) ? 0 : bs + 1;
  }
  VMWAIT(0);
  __builtin_amdgcn_s_barrier();
  __builtin_amdgcn_sched_barrier(0);
  compute(bc);

#pragma unroll
  for (int mi = 0; mi < 4; mi++)
#pragma unroll
    for (int r = 0; r < 4; r++) {
      int qc = q0 + wm * 64 + mi * 16 + quad * 4 + r;
      if (qc < cb) {
#pragma unroll
        for (int ni = 0; ni < 4; ni++) {
          int gt = t0 + wn * 64 + ni * 16 + l16;
          SC[((size_t)b * SEQ + qc) * SEQ + gt] = f2h_bits(acc[mi][ni][r]);
        }
      }
    }
}

// =============================================================================
// sf: fused launch { stats (0..16383) | fill (16384..32767) }.  R13-proven.
// =============================================================================
__global__ __launch_bounds__(256) void sf_kernel(
    const unsigned short* __restrict__ SC, const int* __restrict__ cnt,
    float* __restrict__ Mq, float* __restrict__ Sq,
    const int* __restrict__ mask, const float* __restrict__ Vmean,
    float* __restrict__ out) {
  __shared__ float red[8];
  int bx = blockIdx.x;

  if (bx >= NTOK) {
    int row = bx - NTOK;
    if (mask[row] != 0) return;
    const float* vm = Vmean + (row >> 11) * DB;
    float* o = out + (size_t)row * DB;
    for (int n = threadIdx.x; n < DB; n += 256) o[n] = vm[n] * NORM_F;
    return;
  }

  int b = bx >> 11, qc = bx & 2047;
  if (qc >= cnt[b]) return;
  const unsigned short* p = SC + ((size_t)b * SEQ + qc) * SEQ;
  int tid = threadIdx.x;

  short8 hv = *(const short8*)(p + (tid << 3));
  float v[8];
#pragma unroll
  for (int j = 0; j < 8; j++) v[j] = h2f_bits((unsigned short)hv[j]);

  float m = v[0];
#pragma unroll
  for (int j = 1; j < 8; j++) m = fmaxf(m, v[j]);
#pragma unroll
  for (int off = 32; off >= 1; off >>= 1) m = fmaxf(m, __shfl_down(m, off));

  int w = tid >> 6;
  if ((tid & 63) == 0) red[w] = m;
  __syncthreads();
  m = fmaxf(fmaxf(red[0], red[1]), fmaxf(red[2], red[3]));

  float s = 0.f;
#pragma unroll
  for (int j = 0; j < 8; j++) s += __expf(v[j] - m);
#pragma unroll
  for (int off = 32; off >= 1; off >>= 1) s += __shfl_down(s, off);
  if ((tid & 63) == 0) red[4 + w] = s;
  __syncthreads();
  if (tid == 0) {
    float L = red[4] + red[5] + red[6] + red[7];
    Mq[(size_t)b * SEQ + qc] = m;
    Sq[(size_t)b * SEQ + qc] = NORM_F * ASCALE / L;
  }
}

// =============================================================================
// pv: out[idx[qc]][v] = (1/ASCALE) * sum_t exp(s-m)*scale * V[t][v].
// R13 structure + NEW 4-slot XOR swizzle: B via inverse-swizzled gl_lds source,
// A via swizzled ds_write (reg-staged path CAN scatter), same XOR on reads.
// =============================================================================
__global__ __launch_bounds__(256) void pv_kernel(
    const unsigned short* __restrict__ SC, const unsigned short* __restrict__ VT,
    const int* __restrict__ idx, const int* __restrict__ cnt,
    const float* __restrict__ Mq, const float* __restrict__ Sq,
    float* __restrict__ out) {
  __shared__ unsigned short As[3][64 * 32], Bs[3][128 * 32];   // 36 KB
  int L = blockIdx.x;
  int b = L & 7, tt = L >> 3;                 // 192 per batch
  int q0 = (tt / 6) << 6;                     // 64-row q tiles, q outer
  int v0 = (tt % 6) << 7;                     // v inner (SC stripe L2-reused 6x)
  int cb = cnt[b];
  if (q0 >= cb) return;
  int tid = threadIdx.x;
  int wave = tid >> 6, lane = tid & 63;
  int wm = wave & 1, wn = wave >> 1;          // 2m x 2n waves, each 32x64
  int quad = lane >> 4, l16 = lane & 15;

  int rowA = tid >> 2;
  int colA = (((tid & 3) ^ (rowA & 3)) << 3);               // swizzled A source col
  size_t gaA = ((size_t)b * SEQ + q0 + rowA) * SEQ + colA;  // rows>=cb garbage, guarded
  int lofsA = tid << 3;                                     // linear A dest (swizzled image)
  float mrow = Mq[(size_t)b * SEQ + q0 + rowA];   // rows>=cb: garbage, dead rows
  float srow = Sq[(size_t)b * SEQ + q0 + rowA];
  size_t gb[2]; int lofsB[2];
#pragma unroll
  for (int r = 0; r < 2; r++) {
    int li = r * 256 + tid;
    int row = li >> 2;
    int col = (((li & 3) ^ (row & 3)) << 3);                // inverse-swizzled B source
    gb[r] = ((size_t)b * DB + v0 + row) * SEQ + col;
    lofsB[r] = li << 3;
  }

  f32x4 acc[2][4];
#pragma unroll
  for (int mi = 0; mi < 2; mi++)
#pragma unroll
    for (int ni = 0; ni < 4; ni++) acc[mi][ni] = (f32x4){0.f, 0.f, 0.f, 0.f};

  short8 va[3];   // A reg-stage ring; statically indexed only

  auto ldA = [&](int buf, int kt) {
    if (buf == 0) va[0] = *(const short8*)(SC + gaA + kt);
    else if (buf == 1) va[1] = *(const short8*)(SC + gaA + kt);
    else va[2] = *(const short8*)(SC + gaA + kt);
  };
  auto stageB2 = [&](int buf, int kt) {
#pragma unroll
    for (int r = 0; r < 2; r++)
      gl_lds16(VT + gb[r] + kt, &Bs[buf][lofsB[r]]);
  };
  auto procA = [&](int buf) {
    short8 src = (buf == 0) ? va[0] : ((buf == 1) ? va[1] : va[2]);
    short8 w;
#pragma unroll
    for (int j = 0; j < 8; j++) {
      float x = h2f_bits((unsigned short)src[j]);
      w[j] = (short)f2h_bits(__expf(x - mrow) * srow);
    }
    *(short8*)&As[buf][lofsA] = w;
  };
  int xorq = l16 & 3;                                 // read-side XOR (row&3==l16&3)
  auto compute = [&](int buf) {
    half8 af[2], bfr[4];
#pragma unroll
    for (int mi = 0; mi < 2; mi++)
      af[mi] = *(const half8*)&As[buf][(wm * 32 + mi * 16 + l16) * 32 + ((quad ^ xorq) << 3)];
#pragma unroll
    for (int ni = 0; ni < 4; ni++)
      bfr[ni] = *(const half8*)&Bs[buf][(wn * 64 + ni * 16 + l16) * 32 + ((quad ^ xorq) << 3)];
    __builtin_amdgcn_s_setprio(1);
#pragma unroll
    for (int mi = 0; mi < 2; mi++)
#pragma unroll
      for (int ni = 0; ni < 4; ni++)
        acc[mi][ni] = __builtin_amdgcn_mfma_f32_16x16x32_f16(af[mi], bfr[ni], acc[mi][ni], 0, 0, 0);
    __builtin_amdgcn_s_setprio(0);
  };

  auto body = [&](int it, int C, int S) {
    VMWAIT(3);                 // stage(it) landed: va[C] + all waves' Bs[C]
    procA(C);                  // exp + ds_write A
    LGKM0();                   // retire ds_write (and prior frag reads: WAR)
    __builtin_amdgcn_s_barrier();
    SB0();
    if (it < 62) { ldA(S, (it + 2) * 32); stageB2(S, (it + 2) * 32); }
    compute(C);
    SB0();
  };

  ldA(0, 0);  stageB2(0, 0);
  ldA(1, 32); stageB2(1, 32);
  for (int i3 = 0; i3 < 63; i3 += 3) {
    body(i3, 0, 2);
    body(i3 + 1, 1, 0);
    body(i3 + 2, 2, 1);
  }
  // it = 63 (final tile, buf 0)
  VMWAIT(0);
  procA(0);
  LGKM0();
  __builtin_amdgcn_s_barrier();
  SB0();
  compute(0);

#pragma unroll
  for (int mi = 0; mi < 2; mi++)
#pragma unroll
    for (int r = 0; r < 4; r++) {
      int qc = q0 + wm * 32 + mi * 16 + quad * 4 + r;
      if (qc < cb) {
        int q = idx[b * SEQ + qc];
#pragma unroll
        for (int ni = 0; ni < 4; ni++) {
          int gv = v0 + wn * 64 + ni * 16 + l16;
          out[((size_t)b * SEQ + q) * DB + gv] = acc[mi][ni][r] * INV_ASCALE;
        }
      }
    }
}

// =============================================================================
extern "C" void kernel_launch(void* const* d_in, const int* in_sizes, int n_in,
                              void* d_out, int out_size, void* d_ws, size_t ws_size,
                              hipStream_t stream) {
  const float* x    = (const float*)d_in[0];
  const int*   mask = (const int*)d_in[1];
  const float* Wq   = (const float*)d_in[2];
  const float* bq   = (const float*)d_in[3];
  const float* Wk   = (const float*)d_in[4];
  const float* bk   = (const float*)d_in[5];
  const float* Wv   = (const float*)d_in[6];
  const float* bv   = (const float*)d_in[7];
  float* out = (float*)d_out;
  char* ws = (char*)d_ws;

  const size_t TOKH = (size_t)NTOK * DB * 2;                 // 25,165,824 B
  unsigned short* SC = (unsigned short*)ws;
  unsigned short* Xf = (unsigned short*)ws;
  unsigned short* WT = (unsigned short*)(ws + TOKH);
  const size_t SCSZ = (size_t)BATCH * SEQ * SEQ * 2;         // 67,108,864 B
  unsigned short* Qf = (unsigned short*)(ws + SCSZ);
  unsigned short* Kf = Qf + (size_t)NTOK * DB;
  unsigned short* VT = Kf + (size_t)NTOK * DB;
  int*   idx   = (int*)(ws + SCSZ + 3 * TOKH);
  int*   cnt   = idx + NTOK;
  float* Vmean = (float*)(cnt + 16);
  float* Mq    = Vmean + BATCH * DB;
  float* Sq    = Mq + NTOK;

  prep_kernel<<<6584, 256, 0, stream>>>(x, Xf, Wq, Wk, Wv, WT, mask, idx, cnt);
  proj_kernel<<<(NFUSE / 256) * (NTOK / 256), 512, 0, stream>>>(
      Xf, WT, bq, bk, bv, idx, cnt, Qf, Kf, VT);
  sv_kernel<<<2048 + BATCH * DB, 256, 0, stream>>>(
      Qf, Kf, cnt, SC, VT, Vmean);
  sf_kernel<<<2 * NTOK, 256, 0, stream>>>(
      SC, cnt, Mq, Sq, mask, Vmean, out);
  pv_kernel<<<(SEQ / 64) * (DB / 128) * BATCH, 256, 0, stream>>>(
      SC, VT, idx, cnt, Mq, Sq, out);
}